// Round 18
// baseline (579.281 us; speedup 1.0000x reference)
//
#include <hip/hip_runtime.h>
#include <stdint.h>

#define TT 2048      // T
#define CC 2048      // C
#define NHEAD 16
#define HD 128
#define NB 4         // batch
#define MTOT (NB*TT) // 8192
#define KD 2048      // GEMM K (both projections)
#define NT 32        // K tiles of 64

typedef __attribute__((ext_vector_type(8))) short bf16x8;
typedef __attribute__((ext_vector_type(4))) float f32x4;
typedef __attribute__((ext_vector_type(16))) float f32x16;
typedef __attribute__((ext_vector_type(4))) unsigned u32x4;

__device__ __forceinline__ unsigned short f2bf(float f) {
  unsigned u = __float_as_uint(f);
  u += 0x7FFF + ((u >> 16) & 1);
  return (unsigned short)(u >> 16);
}
__device__ __forceinline__ float bf2f(unsigned short h) {
  return __uint_as_float(((unsigned)h) << 16);
}

__device__ __forceinline__ void gl_lds16(const unsigned short* g, short* l) {
  __builtin_amdgcn_global_load_lds(
      (const __attribute__((address_space(1))) void*)(g),
      (__attribute__((address_space(3))) void*)(l), 16, 0, 0);
}

#define MFMA16(a, b, c) __builtin_amdgcn_mfma_f32_16x16x32_bf16((a), (b), (c), 0, 0, 0)
#define MFMA32(a, b, c) __builtin_amdgcn_mfma_f32_32x32x16_bf16((a), (b), (c), 0, 0, 0)

// ---------------- fp32 -> bf16 cast ----------------
__global__ void k_f2b(const float* __restrict__ in, unsigned short* __restrict__ out, int n4) {
  int i = blockIdx.x * 256 + threadIdx.x;
  if (i >= n4) return;
  float4 v = reinterpret_cast<const float4*>(in)[i];
  ushort4 o;
  o.x = f2bf(v.x); o.y = f2bf(v.y); o.z = f2bf(v.z); o.w = f2bf(v.w);
  reinterpret_cast<ushort4*>(out)[i] = o;
}

// ---------------- RoPE table (fp64 on device; matches np ref closely) ----------------
__global__ void k_rope_tab(float* __restrict__ tab) {
  int t = blockIdx.x, i = threadIdx.x;  // 2048 x 64
  double inv = exp2(-(double)i * (13.287712379549449062 / 64.0)); // 10000^(-i/64)
  double ang = (double)t * inv;
  tab[(t*64 + i)*2 + 0] = (float)cos(ang);
  tab[(t*64 + i)*2 + 1] = (float)sin(ang);
}

// ================= 256x256 8-wave GEMM core, B-direct-from-global =================
// C[m][n] = sum_k A[m][k]*B[n][k]; A:[M][2048], B:[N][2048] row-major bf16 bits.
// LDS-BW roofline fix: only A is LDS-staged (64KB dbuf); B fragments are per-lane
// 16B global loads (L2-resident via mt-fastest XCD swizzle), prefetched one tile
// ahead into registers. Per K-tile: 16 ds_read_b128 + 4 gl_lds (A) + 8 global
// b-loads; ONE barrier; counted vmcnt(8) completes A(t+1), leaves b(t+1) flying.
// Hazard ledger: A(t+1)->other buffer; its readers start only after barrier(t);
// buf(t&1)'s readers all complete before barrier(t) (MFMA consumes reads). B values
// identical to LDS path -> accumulation order unchanged (absmax-invariant).
__device__ __forceinline__ void gemm256_core(
    const unsigned short* __restrict__ Ag,
    const unsigned short* __restrict__ Bg,
    int m0, int n0, short* lds, f32x4 (&acc)[8][4])
{
  const int tid = threadIdx.x;
  const int wid = tid >> 6, lane = tid & 63;
  const int wm = wid >> 2, wn = wid & 3;
  const int r15 = lane & 15, hi4 = lane >> 4;
  const int srow = wid*8 + (lane >> 3);
  const int schunk = (lane & 7) ^ (lane >> 3);

  const f32x4 fz = {0.f, 0.f, 0.f, 0.f};
#pragma unroll
  for (int i = 0; i < 8; i++)
#pragma unroll
    for (int j = 0; j < 4; j++) acc[i][j] = fz;

  int aoff0[8];
#pragma unroll
  for (int mi = 0; mi < 8; mi++) {
    int row = wm*128 + mi*16 + r15;
    aoff0[mi] = row*64 + ((hi4 ^ (row & 7))*8);
  }
  // per-lane B global bases (elements): row = n0 + wn*64 + ni*16 + r15
  const unsigned short* bbase[4];
#pragma unroll
  for (int ni = 0; ni < 4; ni++)
    bbase[ni] = Bg + (size_t)(n0 + wn*64 + ni*16 + r15)*KD + hi4*8;

#define STAGE(L, GROW0, KT) do { \
    gl_lds16(Ag + (size_t)((GROW0) + srow)*KD + (KT) + schunk*8, (L) + wid*512); \
    gl_lds16(Ag + (size_t)((GROW0) + 64 + srow)*KD + (KT) + schunk*8, (L) + 4096 + wid*512); \
  } while(0)

  bf16x8 b[4][2], bn[4][2];
  // prologue: A(0) staged; b(0) loaded to regs
  STAGE(lds,        m0,       0);
  STAGE(lds + 8192, m0 + 128, 0);
#pragma unroll
  for (int ni = 0; ni < 4; ni++) {
    b[ni][0] = *reinterpret_cast<const bf16x8*>(bbase[ni]);
    b[ni][1] = *reinterpret_cast<const bf16x8*>(bbase[ni] + 32);
  }
  asm volatile("s_waitcnt vmcnt(0)" ::: "memory");
  __builtin_amdgcn_s_barrier();
  __builtin_amdgcn_sched_barrier(0);

#pragma unroll 1
  for (int t = 0; t < NT; t++) {
    short* Ab = lds + (t & 1)*16384;
    short* An = lds + ((t & 1) ^ 1)*16384;
    const int kt = t*64;
    const bool stA = (t < NT - 1);

    if (stA) {
      STAGE(An,        m0,       kt + 64);   // 4 gl_lds (issued first)
      STAGE(An + 8192, m0 + 128, kt + 64);
#pragma unroll
      for (int ni = 0; ni < 4; ni++) {       // 8 b-prefetch loads (issued after)
        bn[ni][0] = *reinterpret_cast<const bf16x8*>(bbase[ni] + kt + 64);
        bn[ni][1] = *reinterpret_cast<const bf16x8*>(bbase[ni] + kt + 96);
      }
    }
    bf16x8 a[8];
    // ---- phase 0: kk=0 ----
#pragma unroll
    for (int mi = 0; mi < 8; mi++)
      a[mi] = *reinterpret_cast<const bf16x8*>(Ab + aoff0[mi]);
    __builtin_amdgcn_s_setprio(1);
#pragma unroll
    for (int mi = 0; mi < 8; mi++)
#pragma unroll
      for (int ni = 0; ni < 4; ni++)
        acc[mi][ni] = MFMA16(a[mi], b[ni][0], acc[mi][ni]);
    __builtin_amdgcn_s_setprio(0);
    // ---- phase 1: kk=1 ----
#pragma unroll
    for (int mi = 0; mi < 8; mi++)
      a[mi] = *reinterpret_cast<const bf16x8*>(Ab + (aoff0[mi] ^ 32));
    __builtin_amdgcn_s_setprio(1);
#pragma unroll
    for (int mi = 0; mi < 8; mi++)
#pragma unroll
      for (int ni = 0; ni < 4; ni++)
        acc[mi][ni] = MFMA16(a[mi], b[ni][1], acc[mi][ni]);
    __builtin_amdgcn_s_setprio(0);
    // ---- close tile: A(t+1) landed (vmcnt counts the 8 b-loads still flying) ----
    if (stA) asm volatile("s_waitcnt vmcnt(8)" ::: "memory");
    else     asm volatile("s_waitcnt vmcnt(0)" ::: "memory");
    __builtin_amdgcn_s_barrier();
    __builtin_amdgcn_sched_barrier(0);
#pragma unroll
    for (int ni = 0; ni < 4; ni++) { b[ni][0] = bn[ni][0]; b[ni][1] = bn[ni][1]; }
  }
#undef STAGE
}

// ---------------- QKV projection + scatter + fused RoPE ----------------
__global__ __launch_bounds__(512, 2) void k_qkv(
    const unsigned short* __restrict__ xb,
    const unsigned short* __restrict__ wab,
    const float* __restrict__ tab,
    unsigned short* __restrict__ qr,
    unsigned short* __restrict__ kr,
    unsigned short* __restrict__ vt)
{
  __shared__ __align__(16) short lds[32768];   // A dbuf only, 64KB
  f32x4 acc[8][4];
  int bid = blockIdx.x;                      // 768 blocks = 32 mt x 24 nt
  // mt-fastest XCD swizzle (r16: FETCH 360->152 MB; keeps B panels L2-resident)
  int xcd = bid & 7, idx = bid >> 3;         // idx 0..95
  int m0 = (xcd*4 + (idx & 3))*256;
  int n0 = (idx >> 2)*256;
  gemm256_core(xb, wab, m0, n0, lds, acc);

  int tid = threadIdx.x, wid = tid >> 6, lane = tid & 63;
  int wm = wid >> 2, wn = wid & 3, r15 = lane & 15, hi4 = lane >> 4;
  int nw0 = n0 + wn*64;
  int which = nw0 >> 11;            // 0=q, 1=k, 2=v
  int h = (nw0 & 2047) >> 7;
#pragma unroll
  for (int mi = 0; mi < 8; mi++) {
    int m_base = m0 + wm*128 + mi*16 + hi4*4;
    int b = m_base >> 11;
    int t0 = m_base & (TT - 1);
#pragma unroll
    for (int ni = 0; ni < 4; ni++) {
      int d = (nw0 & 127) + ni*16 + r15;
      if (which == 2) {
        ushort4 pv;
        pv.x = f2bf(acc[mi][ni][0]); pv.y = f2bf(acc[mi][ni][1]);
        pv.z = f2bf(acc[mi][ni][2]); pv.w = f2bf(acc[mi][ni][3]);
        *reinterpret_cast<ushort4*>(vt + ((size_t)((b*NHEAD + h)*HD + d))*TT + t0) = pv;
      } else {
        unsigned short* dst = (which == 0) ? qr : kr;
        size_t base = ((size_t)(b*NHEAD + h)*TT + t0)*HD + d;
        int j = d >> 1;
        bool odd = (d & 1);
#pragma unroll
        for (int r = 0; r < 4; r++) {
          float v = acc[mi][ni][r];
          float pv = __shfl_xor(v, 1);
          float2 cs = *reinterpret_cast<const float2*>(tab + ((size_t)(t0 + r)*64 + j)*2);
          float res = odd ? (pv*cs.y + v*cs.x) : (v*cs.x - pv*cs.y);
          dst[base + (size_t)r*HD] = f2bf(res);
        }
      }
    }
  }
}

// ---------------- output projection ----------------
__global__ __launch_bounds__(512, 2) void k_proj(
    const unsigned short* __restrict__ yb,
    const unsigned short* __restrict__ wpb,
    float* __restrict__ out)
{
  __shared__ __align__(16) short lds[32768];
  f32x4 acc[8][4];
  int bid = blockIdx.x;                      // 256 blocks = 32 mt x 8 nt
  int xcd = bid & 7, idx = bid >> 3;         // idx 0..31
  int m0 = (xcd*4 + (idx & 3))*256;
  int n0 = (idx >> 2)*256;
  gemm256_core(yb, wpb, m0, n0, lds, acc);

  int tid = threadIdx.x, wid = tid >> 6, lane = tid & 63;
  int wm = wid >> 2, wn = wid & 3, r15 = lane & 15, hi4 = lane >> 4;
  int nw0 = n0 + wn*64;
#pragma unroll
  for (int mi = 0; mi < 8; mi++) {
    int m = m0 + wm*128 + mi*16 + hi4*4;
#pragma unroll
    for (int ni = 0; ni < 4; ni++) {
      int n = nw0 + ni*16 + r15;
#pragma unroll
      for (int r = 0; r < 4; r++)
        out[(size_t)(m + r)*CC + n] = acc[mi][ni][r];
    }
  }
}

// ---------------- causal flash attention: swapped-QK^T 32x32, in-register softmax ----------------
// (unchanged from round 14-17 — 8-wave blocks, passed at absmax 0.015625)
__global__ __launch_bounds__(512, 1) void k_attn(
    const unsigned short* __restrict__ qr,
    const unsigned short* __restrict__ kr,
    const unsigned short* __restrict__ vt,
    unsigned short* __restrict__ yb)
{
  __shared__ __align__(16) short Ks[2][64*128];   // [buf][kv][d], chunk-XOR swizzled
  __shared__ __align__(16) short Vs[2][128*64];   // [buf][d][kv], chunk-XOR swizzled
  __shared__ float alds[8][32];                   // per-wave alpha/linv broadcast
  int bid = blockIdx.x;
  int bh = bid & 63, pr = bid >> 6;               // pr 0..3
  int tid = threadIdx.x, w = tid >> 6, lane = tid & 63;
  int l31 = lane & 31, hi = lane >> 5;
  const unsigned short* qg = qr + (size_t)bh*TT*HD;
  const unsigned short* kg = kr + (size_t)bh*TT*HD;
  const unsigned short* vg = vt + (size_t)bh*HD*TT;
  const float scale = 0.08838834764831845f; // 1/sqrt(128)
  int b = bh >> 4, h = bh & 15;

  int ksoff[2], vsoff[2];
#pragma unroll
  for (int i = 0; i < 2; i++) {
    int c = w*2 + i;
    int rK = c*4 + (lane >> 4);
    int cK = (lane & 15) ^ (rK & 7);
    ksoff[i] = rK*HD + cK*8;
    int dV = c*8 + (lane >> 3);
    int cV = (lane & 7) ^ (dV & 7);
    vsoff[i] = dV*TT + cV*8;
  }

#define STAGE_KV(BUF, KV0) do { \
    _Pragma("unroll") \
    for (int i_ = 0; i_ < 2; i_++) { \
      gl_lds16(kg + (size_t)(KV0)*HD + ksoff[i_], &Ks[BUF][(w*2 + i_)*512]); \
      gl_lds16(vg + (KV0) + vsoff[i_],            &Vs[BUF][(w*2 + i_)*512]); \
    } \
  } while(0)

#pragma unroll 1
  for (int ph = 0; ph < 2; ph++) {
    int qb = ph ? (7 - pr) : pr;
    int qlo = qb*256 + w*32;
    int qgi = qlo + l31;
    bf16x8 qf[8];
#pragma unroll
    for (int kk = 0; kk < 8; kk++)
      qf[kk] = *reinterpret_cast<const bf16x8*>(qg + (size_t)qgi*HD + kk*16 + hi*8);

    f32x16 ao[4];
#pragma unroll
    for (int dt = 0; dt < 4; dt++)
#pragma unroll
      for (int r = 0; r < 16; r++) ao[dt][r] = 0.f;
    float mrow = -3.0e38f, lsum = 0.f;
    int ntiles = 4*qb + 4;

    STAGE_KV(0, 0);
    __syncthreads();
    int cur = 0;

#pragma unroll 1
    for (int it = 0; it < ntiles; ++it) {
      int kv0 = it*64;
      if (it + 1 < ntiles) STAGE_KV(cur ^ 1, kv0 + 64);
      if (kv0 <= qlo + 31) {
        const short* Kc = Ks[cur];
        const short* Vc = Vs[cur];
        bool full = (kv0 + 63 <= qlo);
        f32x16 s0, s1;
#pragma unroll
        for (int r = 0; r < 16; r++) { s0[r] = 0.f; s1[r] = 0.f; }
        __builtin_amdgcn_s_setprio(1);
#pragma unroll
        for (int kk = 0; kk < 8; kk++) {
          int row0 = l31, row1 = 32 + l31;
          int ch0 = ((2*kk + hi) ^ (row0 & 7));
          int ch1 = ((2*kk + hi) ^ (row1 & 7));
          bf16x8 kf0 = *reinterpret_cast<const bf16x8*>((const char*)Kc + row0*256 + ch0*16);
          bf16x8 kf1 = *reinterpret_cast<const bf16x8*>((const char*)Kc + row1*256 + ch1*16);
          s0 = MFMA32(kf0, qf[kk], s0);
          s1 = MFMA32(kf1, qf[kk], s1);
        }
        __builtin_amdgcn_s_setprio(0);
        float p[32];
#pragma unroll
        for (int r = 0; r < 16; r++) {
          int kvl = (r & 3) + 8*(r >> 2) + 4*hi;
          float v0 = s0[r]*scale, v1 = s1[r]*scale;
          if (!full) {
            v0 = (kv0 + kvl      <= qgi) ? v0 : -3.0e38f;
            v1 = (kv0 + 32 + kvl <= qgi) ? v1 : -3.0e38f;
          }
          p[r] = v0; p[16 + r] = v1;
        }
        float t16[16];
#pragma unroll
        for (int i = 0; i < 16; i++) t16[i] = fmaxf(p[i], p[i + 16]);
#pragma unroll
        for (int i = 0; i < 8; i++) t16[i] = fmaxf(t16[i], t16[i + 8]);
#pragma unroll
        for (int i = 0; i < 4; i++) t16[i] = fmaxf(t16[i], t16[i + 4]);
        float mx = fmaxf(fmaxf(t16[0], t16[1]), fmaxf(t16[2], t16[3]));
        mx = fmaxf(mx, __shfl_xor(mx, 32));
        bool defer = __all(mx <= mrow + 8.f);
        if (!defer) {
          float mnew = fmaxf(mrow, mx);
          float alpha = __expf(mrow - mnew);
          mrow = mnew;
          lsum *= alpha;
          if (lane < 32) alds[w][lane] = alpha;
#pragma unroll
          for (int r = 0; r < 16; r++) {
            int ql = (r & 3) + 8*(r >> 2) + 4*hi;
            float av = alds[w][ql];
#pragma unroll
            for (int dt = 0; dt < 4; dt++) ao[dt][r] *= av;
          }
        }
#pragma unroll
        for (int i = 0; i < 32; i++) p[i] = __expf(p[i] - mrow);
#pragma unroll
        for (int i = 0; i < 16; i++) t16[i] = p[i] + p[i + 16];
#pragma unroll
        for (int i = 0; i < 8; i++) t16[i] = t16[i] + t16[i + 8];
#pragma unroll
        for (int i = 0; i < 4; i++) t16[i] = t16[i] + t16[i + 4];
        float rs = (t16[0] + t16[1]) + (t16[2] + t16[3]);
        rs += __shfl_xor(rs, 32);
        lsum += rs;
        bf16x8 pa[4];
#pragma unroll
        for (int ks = 0; ks < 4; ks++) {
          const int base = (ks >> 1)*16 + (ks & 1)*8;
          unsigned a0, a1, b0, b1;
          asm("v_cvt_pk_bf16_f32 %0, %1, %2" : "=v"(a0) : "v"(p[base + 0]), "v"(p[base + 1]));
          asm("v_cvt_pk_bf16_f32 %0, %1, %2" : "=v"(a1) : "v"(p[base + 2]), "v"(p[base + 3]));
          asm("v_cvt_pk_bf16_f32 %0, %1, %2" : "=v"(b0) : "v"(p[base + 4]), "v"(p[base + 5]));
          asm("v_cvt_pk_bf16_f32 %0, %1, %2" : "=v"(b1) : "v"(p[base + 6]), "v"(p[base + 7]));
          unsigned sa0 = (unsigned)__shfl_xor((int)a0, 32);
          unsigned sa1 = (unsigned)__shfl_xor((int)a1, 32);
          unsigned sb0 = (unsigned)__shfl_xor((int)b0, 32);
          unsigned sb1 = (unsigned)__shfl_xor((int)b1, 32);
          u32x4 pw;
          pw.x = hi ? sb0 : a0;
          pw.y = hi ? sb1 : a1;
          pw.z = hi ? b0 : sa0;
          pw.w = hi ? b1 : sa1;
          pa[ks] = __builtin_bit_cast(bf16x8, pw);
        }
        __builtin_amdgcn_s_setprio(1);
#pragma unroll
        for (int dt = 0; dt < 4; dt++) {
          int d = dt*32 + l31;
#pragma unroll
          for (int ks = 0; ks < 4; ks++) {
            int ch = ((2*ks + hi) ^ (d & 7));
            bf16x8 vf = *reinterpret_cast<const bf16x8*>((const char*)Vc + d*128 + ch*16);
            ao[dt] = MFMA32(pa[ks], vf, ao[dt]);
          }
        }
        __builtin_amdgcn_s_setprio(0);
      }
      __syncthreads();
      cur ^= 1;
    }
    if (lane < 32) alds[w][lane] = 1.0f / lsum;
#pragma unroll
    for (int r = 0; r < 16; r++) {
      int ql = (r & 3) + 8*(r >> 2) + 4*hi;
      float lv = alds[w][ql];
      int t = qlo + ql;
      size_t base = ((size_t)b*TT + t)*CC + h*HD + l31;
#pragma unroll
      for (int dt = 0; dt < 4; dt++)
        yb[base + dt*32] = f2bf(ao[dt][r] * lv);
    }
    __syncthreads();
  }
#undef STAGE_KV
}

extern "C" void kernel_launch(void* const* d_in, const int* in_sizes, int n_in,
                              void* d_out, int out_size, void* d_ws, size_t ws_size,
                              hipStream_t stream) {
  const float* x  = (const float*)d_in[0];
  const float* wa = (const float*)d_in[1];
  const float* wp = (const float*)d_in[2];
  float* out = (float*)d_out;
  char* ws = (char*)d_ws;
  size_t off = 0;
  unsigned short* xb  = (unsigned short*)(ws + off); off += (size_t)MTOT*CC*2;
  unsigned short* wab = (unsigned short*)(ws + off); off += (size_t)3*CC*CC*2;
  unsigned short* wpb = (unsigned short*)(ws + off); off += (size_t)CC*CC*2;
  unsigned short* qr  = (unsigned short*)(ws + off); off += (size_t)MTOT*CC*2;
  unsigned short* kr  = (unsigned short*)(ws + off); off += (size_t)MTOT*CC*2;
  unsigned short* vt  = (unsigned short*)(ws + off); off += (size_t)MTOT*CC*2;
  unsigned short* yb  = (unsigned short*)(ws + off); off += (size_t)MTOT*CC*2;
  float* tab          = (float*)(ws + off);          off += (size_t)TT*64*2*4;

  k_f2b<<<dim3(16384), dim3(256), 0, stream>>>(x,  xb,  MTOT*CC/4);
  k_f2b<<<dim3(12288), dim3(256), 0, stream>>>(wa, wab, 3*CC*CC/4);
  k_f2b<<<dim3(4096),  dim3(256), 0, stream>>>(wp, wpb, CC*CC/4);
  k_rope_tab<<<dim3(TT), dim3(64), 0, stream>>>(tab);
  k_qkv<<<dim3(768), dim3(512), 0, stream>>>(xb, wab, tab, qr, kr, vt);
  k_attn<<<dim3(256), dim3(512), 0, stream>>>(qr, kr, vt, yb);
  k_proj<<<dim3(256), dim3(512), 0, stream>>>(yb, wpb, out);
}

// Round 19
// 402.059 us; speedup vs baseline: 1.4408x; 1.4408x over previous
//
#include <hip/hip_runtime.h>
#include <stdint.h>

#define TT 2048      // T
#define CC 2048      // C
#define NHEAD 16
#define HD 128
#define NB 4         // batch
#define MTOT (NB*TT) // 8192
#define KD 2048      // GEMM K (both projections)
#define NT 32        // K tiles of 64

typedef __attribute__((ext_vector_type(8))) short bf16x8;
typedef __attribute__((ext_vector_type(4))) float f32x4;
typedef __attribute__((ext_vector_type(16))) float f32x16;
typedef __attribute__((ext_vector_type(4))) unsigned u32x4;

__device__ __forceinline__ unsigned short f2bf(float f) {
  unsigned u = __float_as_uint(f);
  u += 0x7FFF + ((u >> 16) & 1);
  return (unsigned short)(u >> 16);
}
__device__ __forceinline__ float bf2f(unsigned short h) {
  return __uint_as_float(((unsigned)h) << 16);
}

__device__ __forceinline__ void gl_lds16(const unsigned short* g, short* l) {
  __builtin_amdgcn_global_load_lds(
      (const __attribute__((address_space(1))) void*)(g),
      (__attribute__((address_space(3))) void*)(l), 16, 0, 0);
}

#define MFMA16(a, b, c) __builtin_amdgcn_mfma_f32_16x16x32_bf16((a), (b), (c), 0, 0, 0)
#define MFMA32(a, b, c) __builtin_amdgcn_mfma_f32_32x32x16_bf16((a), (b), (c), 0, 0, 0)

#define PRE_MFMA() do { \
  __builtin_amdgcn_s_barrier(); \
  asm volatile("s_waitcnt lgkmcnt(0)" ::: "memory"); \
  __builtin_amdgcn_s_setprio(1); \
} while(0)
#define POST_MFMA() do { \
  __builtin_amdgcn_s_setprio(0); \
  __builtin_amdgcn_s_barrier(); \
  __builtin_amdgcn_sched_barrier(0); \
} while(0)

// ---------------- fp32 -> bf16 cast ----------------
__global__ void k_f2b(const float* __restrict__ in, unsigned short* __restrict__ out, int n4) {
  int i = blockIdx.x * 256 + threadIdx.x;
  if (i >= n4) return;
  float4 v = reinterpret_cast<const float4*>(in)[i];
  ushort4 o;
  o.x = f2bf(v.x); o.y = f2bf(v.y); o.z = f2bf(v.z); o.w = f2bf(v.w);
  reinterpret_cast<ushort4*>(out)[i] = o;
}

// ---------------- RoPE table ----------------
__global__ void k_rope_tab(float* __restrict__ tab) {
  int t = blockIdx.x, i = threadIdx.x;  // 2048 x 64
  double inv = exp2(-(double)i * (13.287712379549449062 / 64.0)); // 10000^(-i/64)
  double ang = (double)t * inv;
  tab[(t*64 + i)*2 + 0] = (float)cos(ang);
  tab[(t*64 + i)*2 + 1] = (float)sin(ang);
}

// ================= 256x256 8-wave 8-PHASE GEMM core (m201 schedule; r16 best) =================
__device__ __forceinline__ void gemm256_core(
    const unsigned short* __restrict__ Ag,
    const unsigned short* __restrict__ Bg,
    int m0, int n0, short* lds, f32x4 (&acc)[2][2][4][2])
{
  const int tid = threadIdx.x;
  const int wid = tid >> 6, lane = tid & 63;
  const int wm = wid >> 2, wn = wid & 3;
  const int r15 = lane & 15, hi4 = lane >> 4;
  const int srow = wid*8 + (lane >> 3);
  const int schunk = (lane & 7) ^ (lane >> 3);

  const f32x4 fz = {0.f, 0.f, 0.f, 0.f};
#pragma unroll
  for (int p = 0; p < 2; p++)
#pragma unroll
    for (int q = 0; q < 2; q++)
#pragma unroll
      for (int i = 0; i < 4; i++)
#pragma unroll
        for (int j = 0; j < 2; j++) acc[p][q][i][j] = fz;

  int aoff[4][2];
#pragma unroll
  for (int mi = 0; mi < 4; mi++)
#pragma unroll
    for (int kk = 0; kk < 2; kk++) {
      int row = wm*64 + mi*16 + r15;
      aoff[mi][kk] = row*64 + (((kk*4 + hi4) ^ (row & 7))*8);
    }
  int boff[2][2];
#pragma unroll
  for (int ni = 0; ni < 2; ni++)
#pragma unroll
    for (int kk = 0; kk < 2; kk++) {
      int row = wn*32 + ni*16 + r15;
      boff[ni][kk] = row*64 + (((kk*4 + hi4) ^ (row & 7))*8);
    }

  short* A0  = lds;            short* A1  = lds + 8192;
  short* A0b = lds + 16384;    short* A1b = lds + 24576;
  short* B0l = lds + 32768;    short* B1l = lds + 40960;
  short* B0b = lds + 49152;    short* B1b = lds + 57344;

#define STAGE(G, L, GROW0, KT) do { \
    gl_lds16((G) + (size_t)((GROW0) + srow)*KD + (KT) + schunk*8, (L) + wid*512); \
    gl_lds16((G) + (size_t)((GROW0) + 64 + srow)*KD + (KT) + schunk*8, (L) + 4096 + wid*512); \
  } while(0)

  STAGE(Ag, A0,  m0,       0);
  STAGE(Bg, B0l, n0,       0);
  STAGE(Bg, B1l, n0 + 128, 0);
  STAGE(Ag, A1,  m0 + 128, 0);
  STAGE(Ag, A0b, m0,       64);
  STAGE(Bg, B0b, n0,       64);
  STAGE(Bg, B1b, n0 + 128, 64);
  asm volatile("s_waitcnt vmcnt(0)" ::: "memory");
  __builtin_amdgcn_s_barrier();
  __builtin_amdgcn_sched_barrier(0);

  bf16x8 a[4][2], b0[2][2], b1[2][2];

#pragma unroll 1
  for (int it = 0; it < 16; it++) {
    const int kt = it*128;
    const bool stP = (it < 15);

    // ---- ph1: tile t, Q(0,0) ----
#pragma unroll
    for (int mi = 0; mi < 4; mi++) {
      a[mi][0] = *reinterpret_cast<const bf16x8*>(A0 + aoff[mi][0]);
      a[mi][1] = *reinterpret_cast<const bf16x8*>(A0 + aoff[mi][1]);
    }
#pragma unroll
    for (int ni = 0; ni < 2; ni++) {
      b0[ni][0] = *reinterpret_cast<const bf16x8*>(B0l + boff[ni][0]);
      b0[ni][1] = *reinterpret_cast<const bf16x8*>(B0l + boff[ni][1]);
    }
    STAGE(Ag, A1b, m0 + 128, kt + 64);
    PRE_MFMA();
#pragma unroll
    for (int mi = 0; mi < 4; mi++)
#pragma unroll
      for (int ni = 0; ni < 2; ni++) {
        acc[0][0][mi][ni] = MFMA16(a[mi][0], b0[ni][0], acc[0][0][mi][ni]);
        acc[0][0][mi][ni] = MFMA16(a[mi][1], b0[ni][1], acc[0][0][mi][ni]);
      }
    POST_MFMA();

    // ---- ph2: Q(0,1) ----
#pragma unroll
    for (int ni = 0; ni < 2; ni++) {
      b1[ni][0] = *reinterpret_cast<const bf16x8*>(B1l + boff[ni][0]);
      b1[ni][1] = *reinterpret_cast<const bf16x8*>(B1l + boff[ni][1]);
    }
    if (stP) STAGE(Ag, A0, m0, kt + 128);
    PRE_MFMA();
#pragma unroll
    for (int mi = 0; mi < 4; mi++)
#pragma unroll
      for (int ni = 0; ni < 2; ni++) {
        acc[0][1][mi][ni] = MFMA16(a[mi][0], b1[ni][0], acc[0][1][mi][ni]);
        acc[0][1][mi][ni] = MFMA16(a[mi][1], b1[ni][1], acc[0][1][mi][ni]);
      }
    POST_MFMA();

    // ---- ph3: Q(1,1) ----
#pragma unroll
    for (int mi = 0; mi < 4; mi++) {
      a[mi][0] = *reinterpret_cast<const bf16x8*>(A1 + aoff[mi][0]);
      a[mi][1] = *reinterpret_cast<const bf16x8*>(A1 + aoff[mi][1]);
    }
    if (stP) STAGE(Bg, B0l, n0, kt + 128);
    PRE_MFMA();
#pragma unroll
    for (int mi = 0; mi < 4; mi++)
#pragma unroll
      for (int ni = 0; ni < 2; ni++) {
        acc[1][1][mi][ni] = MFMA16(a[mi][0], b1[ni][0], acc[1][1][mi][ni]);
        acc[1][1][mi][ni] = MFMA16(a[mi][1], b1[ni][1], acc[1][1][mi][ni]);
      }
    POST_MFMA();

    // ---- ph4: Q(1,0) ----
    if (stP) STAGE(Bg, B1l, n0 + 128, kt + 128);
    if (stP) asm volatile("s_waitcnt vmcnt(6)" ::: "memory");
    else     asm volatile("s_waitcnt vmcnt(0)" ::: "memory");
    PRE_MFMA();
#pragma unroll
    for (int mi = 0; mi < 4; mi++)
#pragma unroll
      for (int ni = 0; ni < 2; ni++) {
        acc[1][0][mi][ni] = MFMA16(a[mi][0], b0[ni][0], acc[1][0][mi][ni]);
        acc[1][0][mi][ni] = MFMA16(a[mi][1], b0[ni][1], acc[1][0][mi][ni]);
      }
    POST_MFMA();

    // ---- ph5: tile t+1, Q(0,0) ----
#pragma unroll
    for (int mi = 0; mi < 4; mi++) {
      a[mi][0] = *reinterpret_cast<const bf16x8*>(A0b + aoff[mi][0]);
      a[mi][1] = *reinterpret_cast<const bf16x8*>(A0b + aoff[mi][1]);
    }
#pragma unroll
    for (int ni = 0; ni < 2; ni++) {
      b0[ni][0] = *reinterpret_cast<const bf16x8*>(B0b + boff[ni][0]);
      b0[ni][1] = *reinterpret_cast<const bf16x8*>(B0b + boff[ni][1]);
    }
    if (stP) STAGE(Ag, A1, m0 + 128, kt + 128);
    PRE_MFMA();
#pragma unroll
    for (int mi = 0; mi < 4; mi++)
#pragma unroll
      for (int ni = 0; ni < 2; ni++) {
        acc[0][0][mi][ni] = MFMA16(a[mi][0], b0[ni][0], acc[0][0][mi][ni]);
        acc[0][0][mi][ni] = MFMA16(a[mi][1], b0[ni][1], acc[0][0][mi][ni]);
      }
    POST_MFMA();

    // ---- ph6: Q(0,1) ----
#pragma unroll
    for (int ni = 0; ni < 2; ni++) {
      b1[ni][0] = *reinterpret_cast<const bf16x8*>(B1b + boff[ni][0]);
      b1[ni][1] = *reinterpret_cast<const bf16x8*>(B1b + boff[ni][1]);
    }
    if (stP) STAGE(Ag, A0b, m0, kt + 192);
    PRE_MFMA();
#pragma unroll
    for (int mi = 0; mi < 4; mi++)
#pragma unroll
      for (int ni = 0; ni < 2; ni++) {
        acc[0][1][mi][ni] = MFMA16(a[mi][0], b1[ni][0], acc[0][1][mi][ni]);
        acc[0][1][mi][ni] = MFMA16(a[mi][1], b1[ni][1], acc[0][1][mi][ni]);
      }
    POST_MFMA();

    // ---- ph7: Q(1,1) ----
#pragma unroll
    for (int mi = 0; mi < 4; mi++) {
      a[mi][0] = *reinterpret_cast<const bf16x8*>(A1b + aoff[mi][0]);
      a[mi][1] = *reinterpret_cast<const bf16x8*>(A1b + aoff[mi][1]);
    }
    if (stP) STAGE(Bg, B0b, n0, kt + 192);
    PRE_MFMA();
#pragma unroll
    for (int mi = 0; mi < 4; mi++)
#pragma unroll
      for (int ni = 0; ni < 2; ni++) {
        acc[1][1][mi][ni] = MFMA16(a[mi][0], b1[ni][0], acc[1][1][mi][ni]);
        acc[1][1][mi][ni] = MFMA16(a[mi][1], b1[ni][1], acc[1][1][mi][ni]);
      }
    POST_MFMA();

    // ---- ph8: Q(1,0) ----
    if (stP) STAGE(Bg, B1b, n0 + 128, kt + 192);
    if (stP) asm volatile("s_waitcnt vmcnt(6)" ::: "memory");
    else     asm volatile("s_waitcnt vmcnt(0)" ::: "memory");
    PRE_MFMA();
#pragma unroll
    for (int mi = 0; mi < 4; mi++)
#pragma unroll
      for (int ni = 0; ni < 2; ni++) {
        acc[1][0][mi][ni] = MFMA16(a[mi][0], b0[ni][0], acc[1][0][mi][ni]);
        acc[1][0][mi][ni] = MFMA16(a[mi][1], b0[ni][1], acc[1][0][mi][ni]);
      }
    POST_MFMA();
  }
#undef STAGE
}

// ---------------- QKV projection + scatter + fused RoPE ----------------
__global__ __launch_bounds__(512, 2) void k_qkv(
    const unsigned short* __restrict__ xb,
    const unsigned short* __restrict__ wab,
    const float* __restrict__ tab,
    unsigned short* __restrict__ qr,
    unsigned short* __restrict__ kr,
    unsigned short* __restrict__ vt)
{
  __shared__ __align__(16) short lds[65536];
  f32x4 acc[2][2][4][2];
  int bid = blockIdx.x;                      // 768 blocks = 32 mt x 24 nt
  int xcd = bid & 7, idx = bid >> 3;         // mt-fastest XCD swizzle (r16)
  int m0 = (xcd*4 + (idx & 3))*256;
  int n0 = (idx >> 2)*256;
  gemm256_core(xb, wab, m0, n0, lds, acc);

  int tid = threadIdx.x, wid = tid >> 6, lane = tid & 63;
  int wm = wid >> 2, wn = wid & 3, r15 = lane & 15, hi4 = lane >> 4;
  int which = n0 >> 11;            // 0=q, 1=k, 2=v
#pragma unroll
  for (int GM = 0; GM < 2; GM++) {
#pragma unroll
    for (int mi = 0; mi < 4; mi++) {
      int m_base = m0 + GM*128 + wm*64 + mi*16 + hi4*4;
      int b = m_base >> 11;
      int t0 = m_base & (TT - 1);
#pragma unroll
      for (int GN = 0; GN < 2; GN++) {
        int h = ((n0 & 2047) >> 7) + GN;
#pragma unroll
        for (int ni = 0; ni < 2; ni++) {
          int d = wn*32 + ni*16 + r15;
          if (which == 2) {
            ushort4 pv;
            pv.x = f2bf(acc[GM][GN][mi][ni][0]); pv.y = f2bf(acc[GM][GN][mi][ni][1]);
            pv.z = f2bf(acc[GM][GN][mi][ni][2]); pv.w = f2bf(acc[GM][GN][mi][ni][3]);
            *reinterpret_cast<ushort4*>(vt + ((size_t)((b*NHEAD + h)*HD + d))*TT + t0) = pv;
          } else {
            unsigned short* dst = (which == 0) ? qr : kr;
            size_t base = ((size_t)(b*NHEAD + h)*TT + t0)*HD + d;
            int j = d >> 1;
            bool odd = (d & 1);
#pragma unroll
            for (int r = 0; r < 4; r++) {
              float v = acc[GM][GN][mi][ni][r];
              float pv = __shfl_xor(v, 1);
              float2 cs = *reinterpret_cast<const float2*>(tab + ((size_t)(t0 + r)*64 + j)*2);
              float res = odd ? (pv*cs.y + v*cs.x) : (v*cs.x - pv*cs.y);
              dst[base + (size_t)r*HD] = f2bf(res);
            }
          }
        }
      }
    }
  }
}

// ---------------- output projection ----------------
__global__ __launch_bounds__(512, 2) void k_proj(
    const unsigned short* __restrict__ yb,
    const unsigned short* __restrict__ wpb,
    float* __restrict__ out)
{
  __shared__ __align__(16) short lds[65536];
  f32x4 acc[2][2][4][2];
  int bid = blockIdx.x;                      // 256 blocks = 32 mt x 8 nt
  int xcd = bid & 7, idx = bid >> 3;
  int m0 = (xcd*4 + (idx & 3))*256;
  int n0 = (idx >> 2)*256;
  gemm256_core(yb, wpb, m0, n0, lds, acc);

  int tid = threadIdx.x, wid = tid >> 6, lane = tid & 63;
  int wm = wid >> 2, wn = wid & 3, r15 = lane & 15, hi4 = lane >> 4;
#pragma unroll
  for (int GM = 0; GM < 2; GM++) {
#pragma unroll
    for (int mi = 0; mi < 4; mi++) {
      int m = m0 + GM*128 + wm*64 + mi*16 + hi4*4;
#pragma unroll
      for (int GN = 0; GN < 2; GN++) {
#pragma unroll
        for (int ni = 0; ni < 2; ni++) {
          int n = n0 + GN*128 + wn*32 + ni*16 + r15;
#pragma unroll
          for (int r = 0; r < 4; r++)
            out[(size_t)(m + r)*CC + n] = acc[GM][GN][mi][ni][r];
        }
      }
    }
  }
}

// ---------------- causal flash attention: swapped-QK^T 32x32, in-register softmax ----------------
__global__ __launch_bounds__(512, 1) void k_attn(
    const unsigned short* __restrict__ qr,
    const unsigned short* __restrict__ kr,
    const unsigned short* __restrict__ vt,
    unsigned short* __restrict__ yb)
{
  __shared__ __align__(16) short Ks[2][64*128];   // [buf][kv][d], chunk-XOR swizzled
  __shared__ __align__(16) short Vs[2][128*64];   // [buf][d][kv], chunk-XOR swizzled
  __shared__ float alds[8][32];                   // per-wave alpha/linv broadcast
  int bid = blockIdx.x;
  int bh = bid & 63, pr = bid >> 6;               // pr 0..3
  int tid = threadIdx.x, w = tid >> 6, lane = tid & 63;
  int l31 = lane & 31, hi = lane >> 5;
  const unsigned short* qg = qr + (size_t)bh*TT*HD;
  const unsigned short* kg = kr + (size_t)bh*TT*HD;
  const unsigned short* vg = vt + (size_t)bh*HD*TT;
  const float scale = 0.08838834764831845f; // 1/sqrt(128)
  int b = bh >> 4, h = bh & 15;

  int ksoff[2], vsoff[2];
#pragma unroll
  for (int i = 0; i < 2; i++) {
    int c = w*2 + i;
    int rK = c*4 + (lane >> 4);
    int cK = (lane & 15) ^ (rK & 7);
    ksoff[i] = rK*HD + cK*8;
    int dV = c*8 + (lane >> 3);
    int cV = (lane & 7) ^ (dV & 7);
    vsoff[i] = dV*TT + cV*8;
  }

#define STAGE_KV(BUF, KV0) do { \
    _Pragma("unroll") \
    for (int i_ = 0; i_ < 2; i_++) { \
      gl_lds16(kg + (size_t)(KV0)*HD + ksoff[i_], &Ks[BUF][(w*2 + i_)*512]); \
      gl_lds16(vg + (KV0) + vsoff[i_],            &Vs[BUF][(w*2 + i_)*512]); \
    } \
  } while(0)

#pragma unroll 1
  for (int ph = 0; ph < 2; ph++) {
    int qb = ph ? (7 - pr) : pr;
    int qlo = qb*256 + w*32;
    int qgi = qlo + l31;
    bf16x8 qf[8];
#pragma unroll
    for (int kk = 0; kk < 8; kk++)
      qf[kk] = *reinterpret_cast<const bf16x8*>(qg + (size_t)qgi*HD + kk*16 + hi*8);

    f32x16 ao[4];
#pragma unroll
    for (int dt = 0; dt < 4; dt++)
#pragma unroll
      for (int r = 0; r < 16; r++) ao[dt][r] = 0.f;
    float mrow = -3.0e38f, lsum = 0.f;
    int ntiles = 4*qb + 4;

    STAGE_KV(0, 0);
    __syncthreads();
    int cur = 0;

#pragma unroll 1
    for (int it = 0; it < ntiles; ++it) {
      int kv0 = it*64;
      if (it + 1 < ntiles) STAGE_KV(cur ^ 1, kv0 + 64);
      if (kv0 <= qlo + 31) {
        const short* Kc = Ks[cur];
        const short* Vc = Vs[cur];
        bool full = (kv0 + 63 <= qlo);
        f32x16 s0, s1;
#pragma unroll
        for (int r = 0; r < 16; r++) { s0[r] = 0.f; s1[r] = 0.f; }
        __builtin_amdgcn_s_setprio(1);
#pragma unroll
        for (int kk = 0; kk < 8; kk++) {
          int row0 = l31, row1 = 32 + l31;
          int ch0 = ((2*kk + hi) ^ (row0 & 7));
          int ch1 = ((2*kk + hi) ^ (row1 & 7));
          bf16x8 kf0 = *reinterpret_cast<const bf16x8*>((const char*)Kc + row0*256 + ch0*16);
          bf16x8 kf1 = *reinterpret_cast<const bf16x8*>((const char*)Kc + row1*256 + ch1*16);
          s0 = MFMA32(kf0, qf[kk], s0);
          s1 = MFMA32(kf1, qf[kk], s1);
        }
        __builtin_amdgcn_s_setprio(0);
        float p[32];
#pragma unroll
        for (int r = 0; r < 16; r++) {
          int kvl = (r & 3) + 8*(r >> 2) + 4*hi;
          float v0 = s0[r]*scale, v1 = s1[r]*scale;
          if (!full) {
            v0 = (kv0 + kvl      <= qgi) ? v0 : -3.0e38f;
            v1 = (kv0 + 32 + kvl <= qgi) ? v1 : -3.0e38f;
          }
          p[r] = v0; p[16 + r] = v1;
        }
        float t16[16];
#pragma unroll
        for (int i = 0; i < 16; i++) t16[i] = fmaxf(p[i], p[i + 16]);
#pragma unroll
        for (int i = 0; i < 8; i++) t16[i] = fmaxf(t16[i], t16[i + 8]);
#pragma unroll
        for (int i = 0; i < 4; i++) t16[i] = fmaxf(t16[i], t16[i + 4]);
        float mx = fmaxf(fmaxf(t16[0], t16[1]), fmaxf(t16[2], t16[3]));
        mx = fmaxf(mx, __shfl_xor(mx, 32));
        bool defer = __all(mx <= mrow + 8.f);
        if (!defer) {
          float mnew = fmaxf(mrow, mx);
          float alpha = __expf(mrow - mnew);
          mrow = mnew;
          lsum *= alpha;
          if (lane < 32) alds[w][lane] = alpha;
#pragma unroll
          for (int r = 0; r < 16; r++) {
            int ql = (r & 3) + 8*(r >> 2) + 4*hi;
            float av = alds[w][ql];
#pragma unroll
            for (int dt = 0; dt < 4; dt++) ao[dt][r] *= av;
          }
        }
#pragma unroll
        for (int i = 0; i < 32; i++) p[i] = __expf(p[i] - mrow);
#pragma unroll
        for (int i = 0; i < 16; i++) t16[i] = p[i] + p[i + 16];
#pragma unroll
        for (int i = 0; i < 8; i++) t16[i] = t16[i] + t16[i + 8];
#pragma unroll
        for (int i = 0; i < 4; i++) t16[i] = t16[i] + t16[i + 4];
        float rs = (t16[0] + t16[1]) + (t16[2] + t16[3]);
        rs += __shfl_xor(rs, 32);
        lsum += rs;
        bf16x8 pa[4];
#pragma unroll
        for (int ks = 0; ks < 4; ks++) {
          const int base = (ks >> 1)*16 + (ks & 1)*8;
          unsigned a0, a1, b0, b1;
          asm("v_cvt_pk_bf16_f32 %0, %1, %2" : "=v"(a0) : "v"(p[base + 0]), "v"(p[base + 1]));
          asm("v_cvt_pk_bf16_f32 %0, %1, %2" : "=v"(a1) : "v"(p[base + 2]), "v"(p[base + 3]));
          asm("v_cvt_pk_bf16_f32 %0, %1, %2" : "=v"(b0) : "v"(p[base + 4]), "v"(p[base + 5]));
          asm("v_cvt_pk_bf16_f32 %0, %1, %2" : "=v"(b1) : "v"(p[base + 6]), "v"(p[base + 7]));
          unsigned sa0 = (unsigned)__shfl_xor((int)a0, 32);
          unsigned sa1 = (unsigned)__shfl_xor((int)a1, 32);
          unsigned sb0 = (unsigned)__shfl_xor((int)b0, 32);
          unsigned sb1 = (unsigned)__shfl_xor((int)b1, 32);
          u32x4 pw;
          pw.x = hi ? sb0 : a0;
          pw.y = hi ? sb1 : a1;
          pw.z = hi ? b0 : sa0;
          pw.w = hi ? b1 : sa1;
          pa[ks] = __builtin_bit_cast(bf16x8, pw);
        }
        __builtin_amdgcn_s_setprio(1);
#pragma unroll
        for (int dt = 0; dt < 4; dt++) {
          int d = dt*32 + l31;
#pragma unroll
          for (int ks = 0; ks < 4; ks++) {
            int ch = ((2*ks + hi) ^ (d & 7));
            bf16x8 vf = *reinterpret_cast<const bf16x8*>((const char*)Vc + d*128 + ch*16);
            ao[dt] = MFMA32(pa[ks], vf, ao[dt]);
          }
        }
        __builtin_amdgcn_s_setprio(0);
      }
      __syncthreads();
      cur ^= 1;
    }
    if (lane < 32) alds[w][lane] = 1.0f / lsum;
#pragma unroll
    for (int r = 0; r < 16; r++) {
      int ql = (r & 3) + 8*(r >> 2) + 4*hi;
      float lv = alds[w][ql];
      int t = qlo + ql;
      size_t base = ((size_t)b*TT + t)*CC + h*HD + l31;
#pragma unroll
      for (int dt = 0; dt < 4; dt++)
        yb[base + dt*32] = f2bf(ao[dt][r] * lv);
    }
    __syncthreads();
  }
#undef STAGE_KV
}

extern "C" void kernel_launch(void* const* d_in, const int* in_sizes, int n_in,
                              void* d_out, int out_size, void* d_ws, size_t ws_size,
                              hipStream_t stream) {
  const float* x  = (const float*)d_in[0];
  const float* wa = (const float*)d_in[1];
  const float* wp = (const float*)d_in[2];
  float* out = (float*)d_out;
  char* ws = (char*)d_ws;
  size_t off = 0;
  unsigned short* xb  = (unsigned short*)(ws + off); off += (size_t)MTOT*CC*2;
  unsigned short* wab = (unsigned short*)(ws + off); off += (size_t)3*CC*CC*2;
  unsigned short* wpb = (unsigned short*)(ws + off); off += (size_t)CC*CC*2;
  unsigned short* qr  = (unsigned short*)(ws + off); off += (size_t)MTOT*CC*2;
  unsigned short* kr  = (unsigned short*)(ws + off); off += (size_t)MTOT*CC*2;
  unsigned short* vt  = (unsigned short*)(ws + off); off += (size_t)MTOT*CC*2;
  unsigned short* yb  = (unsigned short*)(ws + off); off += (size_t)MTOT*CC*2;
  float* tab          = (float*)(ws + off);          off += (size_t)TT*64*2*4;

  k_f2b<<<dim3(16384), dim3(256), 0, stream>>>(x,  xb,  MTOT*CC/4);
  k_f2b<<<dim3(12288), dim3(256), 0, stream>>>(wa, wab, 3*CC*CC/4);
  k_f2b<<<dim3(4096),  dim3(256), 0, stream>>>(wp, wpb, CC*CC/4);
  k_rope_tab<<<dim3(TT), dim3(64), 0, stream>>>(tab);
  k_qkv<<<dim3(768), dim3(512), 0, stream>>>(xb, wab, tab, qr, kr, vt);
  k_attn<<<dim3(256), dim3(512), 0, stream>>>(qr, kr, vt, yb);
  k_proj<<<dim3(256), dim3(512), 0, stream>>>(yb, wpb, out);
}